// Round 3
// baseline (1719.767 us; speedup 1.0000x reference)
//
#include <hip/hip_runtime.h>
#include <math.h>

#define VOXN 32768

// ---- workspace layout (float offsets) ----
constexpr int OFF_STATS_Y   = 0;        // 512  (sum[256], sumsq[256])
constexpr int OFF_STATS_X2P = 512;      // 256  (sum[128], sumsq[128])
constexpr int OFF_STATS_H   = 768;      // 512  (sum[256], sumsq[256])
constexpr int OFF_PVOL      = 1280;     // 46656 padded 36^3 volume
constexpr int OFF_TPAR      = 48000;    // 1024*32 words (int+float mixed)
constexpr int OFF_W1T       = 80768;    // 65536: w1t[g][c][o] = w1[g][o][c]
constexpr int OFF_W2T       = 146304;   // 32768: w2t[c][o]
constexpr int OFF_W3AT      = 179072;   // 4096
constexpr int OFF_W3BT      = 183168;   // 5120
constexpr int OFF_W3CT      = 188288;   // 6144
constexpr int OFF_W3DT      = 194432;   // 7168
constexpr int OFF_W4T       = 201600;   // 2048
constexpr int OFF_YH        = 203648;   // 8388608 (y, later reused as H)
constexpr int OFF_X2P       = 8592256;  // 4194304

// Fully-unrolled (static-index) wave reduce + atomic.
template<int NO>
__device__ __forceinline__ void reduce_atomic(float* acc, float* __restrict__ stats,
                                              int base, int sq_off, int lane)
{
  #pragma unroll
  for (int o = 0; o < NO; ++o) {
    float s = acc[o], q = acc[o] * acc[o];
    #pragma unroll
    for (int m = 32; m; m >>= 1) { s += __shfl_xor(s, m, 64); q += __shfl_xor(q, m, 64); }
    if (lane == 0) { atomicAdd(&stats[base + o], s); atomicAdd(&stats[sq_off + base + o], q); }
  }
}

// ---------------- S0: setup ----------------
__global__ void s0_setup(const float* __restrict__ images, const float* __restrict__ offset1,
                         const float* __restrict__ w1, const float* __restrict__ w2,
                         const float* __restrict__ w3a, const float* __restrict__ w3b,
                         const float* __restrict__ w3c, const float* __restrict__ w3d,
                         const float* __restrict__ w4, float* __restrict__ ws)
{
  const int idx = blockIdx.x * blockDim.x + threadIdx.x;
  const int stride = gridDim.x * blockDim.x;
  for (int i = idx; i < 1280; i += stride) ws[i] = 0.f;
  for (int i = idx; i < 46656; i += stride) {
    int x = i % 36, t = i / 36, y = t % 36, z = t / 36;
    int xo = x - 2, yo = y - 2, zo = z - 2;
    float val = 0.f;
    if ((unsigned)xo < 32u && (unsigned)yo < 32u && (unsigned)zo < 32u)
      val = images[(zo * 32 + yo) * 32 + xo];
    ws[OFF_PVOL + i] = val;
  }
  for (int k = idx; k < 1024; k += stride) {
    int*   tpi = reinterpret_cast<int*>(ws + OFF_TPAR) + (k << 5);
    float* tpf = ws + OFF_TPAR + (k << 5);
    int dxi[2], dyi[2], dzi[2]; float wx0[2], wx1[2], zz[2][4];
    for (int s = 0; s < 2; ++s) {
      float ox = offset1[k * 6 + s * 3 + 0] * 16.f;
      float oy = offset1[k * 6 + s * 3 + 1] * 16.f;
      float oz = offset1[k * 6 + s * 3 + 2] * 16.f;
      ox = fminf(fmaxf(ox, -100.f), 100.f);
      oy = fminf(fmaxf(oy, -100.f), 100.f);
      oz = fminf(fmaxf(oz, -100.f), 100.f);
      float fxf = floorf(ox), fyf = floorf(oy), fzf = floorf(oz);
      float fx = ox - fxf, fy = oy - fyf, fz = oz - fzf;
      dxi[s] = (int)fxf + 2; dyi[s] = (int)fyf + 2; dzi[s] = (int)fzf + 2;
      wx0[s] = 1.f - fx; wx1[s] = fx;
      float wy0 = 1.f - fy, wy1 = fy, wz0 = 1.f - fz, wz1 = fz;
      float sgn = s ? -1.f : 1.f;
      zz[s][0] = sgn * wz0 * wy0; zz[s][1] = sgn * wz0 * wy1;
      zz[s][2] = sgn * wz1 * wy0; zz[s][3] = sgn * wz1 * wy1;
    }
    tpi[0] = dxi[0]; tpi[1] = dyi[0]; tpi[2] = dzi[0]; tpi[3] = dxi[1];
    tpi[4] = dyi[1]; tpi[5] = dzi[1]; tpi[6] = 0; tpi[7] = 0;
    tpf[8]  = wx0[0]; tpf[9]  = wx1[0]; tpf[10] = zz[0][0]; tpf[11] = zz[0][1];
    tpf[12] = zz[0][2]; tpf[13] = zz[0][3]; tpf[14] = wx0[1]; tpf[15] = wx1[1];
    tpf[16] = zz[1][0]; tpf[17] = zz[1][1]; tpf[18] = zz[1][2]; tpf[19] = zz[1][3];
  }
  for (int i = idx; i < 65536; i += stride) {
    int o = i & 63, t = i >> 6, c = t & 255, gg = t >> 8;
    ws[OFF_W1T + i] = w1[gg * 16384 + o * 256 + c];
  }
  for (int i = idx; i < 32768; i += stride) { int o = i & 127, c = i >> 7; ws[OFF_W2T + i] = w2[o * 256 + c]; }
  for (int i = idx; i < 4096;  i += stride) { int o = i & 31,  c = i >> 5; ws[OFF_W3AT + i] = w3a[o * 128 + c]; }
  for (int i = idx; i < 5120;  i += stride) { int o = i & 31,  c = i >> 5; ws[OFF_W3BT + i] = w3b[o * 160 + c]; }
  for (int i = idx; i < 6144;  i += stride) { int o = i & 31,  c = i >> 5; ws[OFF_W3CT + i] = w3c[o * 192 + c]; }
  for (int i = idx; i < 7168;  i += stride) { int o = i & 31,  c = i >> 5; ws[OFF_W3DT + i] = w3d[o * 224 + c]; }
  for (int i = idx; i < 2048;  i += stride) { int l = i & 7,   c = i >> 3; ws[OFF_W4T + i] = w4[l * 256 + c]; }
}

// ---------------- S1: fused gather + grouped GEMM (y = w1 @ x) ----------------
// Block: 512 thr = 8 waves over 128 voxels, one group g.
// Wave w: o-quarter q=w&3 (16 outputs), v-half vh=w>>2 (64 voxels).
// Per k-chunk of 4: wave gathers sub-k q for its 64 voxels -> LDS; all waves
// then accumulate 4 sub-k x 16 outputs from LDS. acc[16] per thread.
__global__ __launch_bounds__(512) void s1_gather_gemm(
    const float* __restrict__ pvol, const int* __restrict__ tpar,
    const float* __restrict__ w1t, float* __restrict__ y, float* __restrict__ stats_y)
{
  __shared__ float xs[2][4][128];
  const int tid  = threadIdx.x;
  const int lane = tid & 63;
  const int w    = tid >> 6;     // 0..7
  const int q    = w & 3;        // o-quarter & gather sub-k
  const int vh   = w >> 2;       // 0..1
  const int g    = blockIdx.x >> 8;   // 0..3
  const int tile = blockIdx.x & 255;  // 0..255
  const int v    = tile * 128 + vh * 64 + lane;
  const int xv = v & 31, yv = (v >> 5) & 31, zv = v >> 10;
  const int kbase = g << 8;

  float acc[16];
  #pragma unroll
  for (int o = 0; o < 16; ++o) acc[o] = 0.f;

  for (int kc = 0; kc < 256; kc += 4) {
    const int buf = (kc >> 2) & 1;
    // ---- gather xval for k = kbase + kc + q, voxel v ----
    const int* tp = tpar + ((kbase + kc + q) << 5);
    int4 ia = *(const int4*)(tp);
    int4 ib = *(const int4*)(tp + 4);
    float4 fa = *(const float4*)((const float*)tp + 8);
    float4 fb = *(const float4*)((const float*)tp + 12);
    float4 fc = *(const float4*)((const float*)tp + 16);
    float xval;
    {
      int xc = min(max(xv + ia.x, 0), 34);
      int yc = min(max(yv + ia.y, 0), 34);
      int zc = min(max(zv + ia.z, 0), 34);
      int r0 = (zc * 36 + yc) * 36 + xc;
      float v00 = pvol[r0],        v01 = pvol[r0 + 1];
      float v10 = pvol[r0 + 36],   v11 = pvol[r0 + 37];
      float v20 = pvol[r0 + 1296], v21 = pvol[r0 + 1297];
      float v30 = pvol[r0 + 1332], v31 = pvol[r0 + 1333];
      float h00 = v00 * fa.x + v01 * fa.y, h01 = v10 * fa.x + v11 * fa.y;
      float h10 = v20 * fa.x + v21 * fa.y, h11 = v30 * fa.x + v31 * fa.y;
      xval = fa.z * h00 + fa.w * h01 + fb.x * h10 + fb.y * h11;
    }
    {
      int xc = min(max(xv + ia.w, 0), 34);
      int yc = min(max(yv + ib.x, 0), 34);
      int zc = min(max(zv + ib.y, 0), 34);
      int r0 = (zc * 36 + yc) * 36 + xc;
      float v00 = pvol[r0],        v01 = pvol[r0 + 1];
      float v10 = pvol[r0 + 36],   v11 = pvol[r0 + 37];
      float v20 = pvol[r0 + 1296], v21 = pvol[r0 + 1297];
      float v30 = pvol[r0 + 1332], v31 = pvol[r0 + 1333];
      float h00 = v00 * fb.z + v01 * fb.w, h01 = v10 * fb.z + v11 * fb.w;
      float h10 = v20 * fb.z + v21 * fb.w, h11 = v30 * fb.z + v31 * fb.w;
      xval += fc.x * h00 + fc.y * h01 + fc.z * h10 + fc.w * h11; // fc pre-negated
    }
    xs[buf][q][vh * 64 + lane] = xval;
    __syncthreads();
    // ---- accumulate: 4 sub-k x 16 outputs ----
    #pragma unroll
    for (int sub = 0; sub < 4; ++sub) {
      float x = xs[buf][sub][vh * 64 + lane];
      const float4* wk4 = (const float4*)(w1t + ((size_t)(kbase + kc + sub) << 6) + (q << 4));
      #pragma unroll
      for (int oq = 0; oq < 4; ++oq) {
        float4 wv = wk4[oq];
        acc[oq * 4 + 0] = fmaf(wv.x, x, acc[oq * 4 + 0]);
        acc[oq * 4 + 1] = fmaf(wv.y, x, acc[oq * 4 + 1]);
        acc[oq * 4 + 2] = fmaf(wv.z, x, acc[oq * 4 + 2]);
        acc[oq * 4 + 3] = fmaf(wv.w, x, acc[oq * 4 + 3]);
      }
    }
  }
  const int obase = (g << 6) + (q << 4);
  #pragma unroll
  for (int o = 0; o < 16; ++o)
    y[((size_t)(obase + o)) * VOXN + v] = acc[o];
  reduce_atomic<16>(acc, stats_y, obase, 256, lane);
}

// ---------------- S2: x1 = relu(BN(y)); x2pre = w2 @ x1 (16 outputs per block) ----------------
__global__ __launch_bounds__(256) void s2_bn_gemm(
    const float* __restrict__ y, const float* __restrict__ stats_y,
    const float* __restrict__ g1, const float* __restrict__ b1,
    const float* __restrict__ w2t, float* __restrict__ x2p, float* __restrict__ stats_x2p)
{
  __shared__ float As[256], Bs[256];
  const int tid = threadIdx.x;
  {
    float m = stats_y[tid] * (1.f / VOXN);
    float vv = stats_y[256 + tid] * (1.f / VOXN) - m * m;
    float a = g1[tid] * rsqrtf(vv + 1e-5f);
    As[tid] = a; Bs[tid] = b1[tid] - m * a;
  }
  __syncthreads();
  const int q = blockIdx.y;            // 0..7 -> outputs q*16..q*16+15
  const int n = blockIdx.x * 256 + tid;
  float acc[16];
  #pragma unroll
  for (int o = 0; o < 16; ++o) acc[o] = 0.f;
  for (int c = 0; c < 256; ++c) {
    float t = fmaxf(fmaf(y[(size_t)c * VOXN + n], As[c], Bs[c]), 0.f);
    const float4* wk4 = (const float4*)(w2t + c * 128 + q * 16);
    #pragma unroll
    for (int oq = 0; oq < 4; ++oq) {
      float4 wv = wk4[oq];
      acc[oq * 4 + 0] = fmaf(wv.x, t, acc[oq * 4 + 0]);
      acc[oq * 4 + 1] = fmaf(wv.y, t, acc[oq * 4 + 1]);
      acc[oq * 4 + 2] = fmaf(wv.z, t, acc[oq * 4 + 2]);
      acc[oq * 4 + 3] = fmaf(wv.w, t, acc[oq * 4 + 3]);
    }
  }
  const int lane = tid & 63;
  #pragma unroll
  for (int o = 0; o < 16; ++o) x2p[((size_t)(q * 16 + o)) * VOXN + n] = acc[o];
  reduce_atomic<16>(acc, stats_x2p, q * 16, 128, lane);
}

// ---------------- S3: x2 = BN(x2pre) -> H[0:128]; h_a = relu(w3a@x2) -> H[128:160] ----------------
__global__ __launch_bounds__(256) void s3_x2_ha(
    const float* __restrict__ x2p, const float* __restrict__ stats_x2p,
    const float* __restrict__ g2, const float* __restrict__ b2,
    const float* __restrict__ w3at, float* __restrict__ H, float* __restrict__ stats_H)
{
  __shared__ float As[128], Bs[128];
  const int tid = threadIdx.x;
  if (tid < 128) {
    float m = stats_x2p[tid] * (1.f / VOXN);
    float vv = stats_x2p[128 + tid] * (1.f / VOXN) - m * m;
    float a = g2[tid] * rsqrtf(vv + 1e-5f);
    As[tid] = a; Bs[tid] = b2[tid] - m * a;
    if (blockIdx.x == 0 && blockIdx.y == 0) {
      float mean = b2[tid];
      float var = a * a * vv;
      stats_H[tid] = mean * (float)VOXN;
      stats_H[256 + tid] = (var + mean * mean) * (float)VOXN;
    }
  }
  __syncthreads();
  const int half = blockIdx.y;         // 0..1 -> outputs half*16..+15
  const int n = blockIdx.x * 256 + tid;
  float acc[16];
  #pragma unroll
  for (int o = 0; o < 16; ++o) acc[o] = 0.f;
  for (int c = 0; c < 128; ++c) {
    float x2v = fmaf(x2p[(size_t)c * VOXN + n], As[c], Bs[c]);
    if (half == 0) H[(size_t)c * VOXN + n] = x2v;
    const float4* wk4 = (const float4*)(w3at + c * 32 + half * 16);
    #pragma unroll
    for (int oq = 0; oq < 4; ++oq) {
      float4 wv = wk4[oq];
      acc[oq * 4 + 0] = fmaf(wv.x, x2v, acc[oq * 4 + 0]);
      acc[oq * 4 + 1] = fmaf(wv.y, x2v, acc[oq * 4 + 1]);
      acc[oq * 4 + 2] = fmaf(wv.z, x2v, acc[oq * 4 + 2]);
      acc[oq * 4 + 3] = fmaf(wv.w, x2v, acc[oq * 4 + 3]);
    }
  }
  const int lane = tid & 63;
  #pragma unroll
  for (int o = 0; o < 16; ++o) {
    float h = fmaxf(acc[o], 0.f);
    acc[o] = h;
    H[((size_t)(128 + half * 16 + o)) * VOXN + n] = h;
  }
  reduce_atomic<16>(acc, stats_H, 128 + half * 16, 256, lane);
}

// ---------------- S4/5/6: h = relu(w @ BN(H[0:CIN])) -> H[och+osub .. +16] ----------------
template<int CIN>
__global__ __launch_bounds__(256) void s_dense(
    const float* __restrict__ Hin, const float* __restrict__ stats_H,
    const float* __restrict__ g, const float* __restrict__ b,
    const float* __restrict__ wt, float* __restrict__ H, float* __restrict__ stats_out, int och)
{
  __shared__ float As[CIN], Bs[CIN];
  const int tid = threadIdx.x;
  if (tid < CIN) {
    float m = stats_H[tid] * (1.f / VOXN);
    float vv = stats_H[256 + tid] * (1.f / VOXN) - m * m;
    float a = g[tid] * rsqrtf(vv + 1e-5f);
    As[tid] = a; Bs[tid] = b[tid] - m * a;
  }
  __syncthreads();
  const int osub = blockIdx.y * 16;    // 0 or 16
  const int n = blockIdx.x * 256 + tid;
  float acc[16];
  #pragma unroll
  for (int o = 0; o < 16; ++o) acc[o] = 0.f;
  for (int c = 0; c < CIN; ++c) {
    float t = fmaf(Hin[(size_t)c * VOXN + n], As[c], Bs[c]);
    const float4* wk4 = (const float4*)(wt + c * 32 + osub);
    #pragma unroll
    for (int oq = 0; oq < 4; ++oq) {
      float4 wv = wk4[oq];
      acc[oq * 4 + 0] = fmaf(wv.x, t, acc[oq * 4 + 0]);
      acc[oq * 4 + 1] = fmaf(wv.y, t, acc[oq * 4 + 1]);
      acc[oq * 4 + 2] = fmaf(wv.z, t, acc[oq * 4 + 2]);
      acc[oq * 4 + 3] = fmaf(wv.w, t, acc[oq * 4 + 3]);
    }
  }
  const int lane = tid & 63;
  #pragma unroll
  for (int o = 0; o < 16; ++o) {
    float h = fmaxf(acc[o], 0.f);
    acc[o] = h;
    H[((size_t)(och + osub + o)) * VOXN + n] = h;
  }
  reduce_atomic<16>(acc, stats_out, och + osub, 256, lane);
}

// ---------------- S7: out = sigmoid(w4 @ BN(H) + b4) ----------------
__global__ __launch_bounds__(256) void s7_final(
    const float* __restrict__ H, const float* __restrict__ stats_H,
    const float* __restrict__ g3d, const float* __restrict__ b3d,
    const float* __restrict__ w4t, const float* __restrict__ b4, float* __restrict__ out)
{
  __shared__ float As[256], Bs[256];
  const int tid = threadIdx.x;
  {
    float m = stats_H[tid] * (1.f / VOXN);
    float vv = stats_H[256 + tid] * (1.f / VOXN) - m * m;
    float a = g3d[tid] * rsqrtf(vv + 1e-5f);
    As[tid] = a; Bs[tid] = b3d[tid] - m * a;
  }
  __syncthreads();
  const int n = blockIdx.x * 256 + tid;
  float acc[8];
  #pragma unroll
  for (int l = 0; l < 8; ++l) acc[l] = 0.f;
  for (int c = 0; c < 256; ++c) {
    float t = fmaf(H[(size_t)c * VOXN + n], As[c], Bs[c]);
    const float4* wk4 = (const float4*)(w4t + c * 8);
    float4 w0 = wk4[0], w1v = wk4[1];
    acc[0] = fmaf(w0.x, t, acc[0]);  acc[1] = fmaf(w0.y, t, acc[1]);
    acc[2] = fmaf(w0.z, t, acc[2]);  acc[3] = fmaf(w0.w, t, acc[3]);
    acc[4] = fmaf(w1v.x, t, acc[4]); acc[5] = fmaf(w1v.y, t, acc[5]);
    acc[6] = fmaf(w1v.z, t, acc[6]); acc[7] = fmaf(w1v.w, t, acc[7]);
  }
  #pragma unroll
  for (int l = 0; l < 8; ++l) {
    float xv = acc[l] + b4[l];
    out[(size_t)l * VOXN + n] = 1.f / (1.f + expf(-xv));
  }
}

extern "C" void kernel_launch(void* const* d_in, const int* in_sizes, int n_in,
                              void* d_out, int out_size, void* d_ws, size_t ws_size,
                              hipStream_t stream)
{
  const float* images  = (const float*)d_in[0];
  const float* offset1 = (const float*)d_in[1];
  const float* w1  = (const float*)d_in[2];
  const float* g1  = (const float*)d_in[3];
  const float* b1  = (const float*)d_in[4];
  const float* w2  = (const float*)d_in[5];
  const float* g2  = (const float*)d_in[6];
  const float* b2  = (const float*)d_in[7];
  const float* w3a = (const float*)d_in[8];
  const float* w3b = (const float*)d_in[9];
  const float* w3c = (const float*)d_in[10];
  const float* w3d = (const float*)d_in[11];
  const float* g3a = (const float*)d_in[12];
  const float* b3a = (const float*)d_in[13];
  const float* g3b = (const float*)d_in[14];
  const float* b3b = (const float*)d_in[15];
  const float* g3c = (const float*)d_in[16];
  const float* b3c = (const float*)d_in[17];
  const float* g3d = (const float*)d_in[18];
  const float* b3d = (const float*)d_in[19];
  const float* w4  = (const float*)d_in[20];
  const float* b4  = (const float*)d_in[21];

  float* ws  = (float*)d_ws;
  float* out = (float*)d_out;

  float* statsY = ws + OFF_STATS_Y;
  float* statsX = ws + OFF_STATS_X2P;
  float* statsH = ws + OFF_STATS_H;
  float* pvol   = ws + OFF_PVOL;
  float* w1t    = ws + OFF_W1T;
  float* w2t    = ws + OFF_W2T;
  float* YH     = ws + OFF_YH;   // y, later H
  float* x2p    = ws + OFF_X2P;

  s0_setup<<<dim3(64), dim3(256), 0, stream>>>(images, offset1, w1, w2, w3a, w3b, w3c, w3d, w4, ws);
  s1_gather_gemm<<<dim3(1024), dim3(512), 0, stream>>>(pvol, (const int*)(ws + OFF_TPAR), w1t, YH, statsY);
  s2_bn_gemm<<<dim3(128, 8), dim3(256), 0, stream>>>(YH, statsY, g1, b1, w2t, x2p, statsX);
  s3_x2_ha<<<dim3(128, 2), dim3(256), 0, stream>>>(x2p, statsX, g2, b2, ws + OFF_W3AT, YH, statsH);
  s_dense<160><<<dim3(128, 2), dim3(256), 0, stream>>>(YH, statsH, g3a, b3a, ws + OFF_W3BT, YH, statsH, 160);
  s_dense<192><<<dim3(128, 2), dim3(256), 0, stream>>>(YH, statsH, g3b, b3b, ws + OFF_W3CT, YH, statsH, 192);
  s_dense<224><<<dim3(128, 2), dim3(256), 0, stream>>>(YH, statsH, g3c, b3c, ws + OFF_W3DT, YH, statsH, 224);
  s7_final<<<dim3(128), dim3(256), 0, stream>>>(YH, statsH, g3d, b3d, ws + OFF_W4T, b4, out);
}

// Round 4
// 1421.677 us; speedup vs baseline: 1.2097x; 1.2097x over previous
//
#include <hip/hip_runtime.h>
#include <math.h>

#define VOXN 32768

// ---- workspace layout (float offsets) ----
constexpr int OFF_STATS_Y   = 0;        // 512  (sum[256], sumsq[256])
constexpr int OFF_STATS_X2P = 512;      // 256  (sum[128], sumsq[128])
constexpr int OFF_STATS_H   = 768;      // 512  (sum[256], sumsq[256])
constexpr int OFF_PVOL      = 1280;     // 46656 padded 36^3 volume
constexpr int OFF_TPAR      = 48000;    // 1024*32 words (int+float mixed)
constexpr int OFF_W1T       = 80768;    // 65536: w1t[g][c][o] = w1[g][o][c]
constexpr int OFF_W2T       = 146304;   // 32768: w2t[c][o]
constexpr int OFF_W3AT      = 179072;   // 4096
constexpr int OFF_W3BT      = 183168;   // 5120
constexpr int OFF_W3CT      = 188288;   // 6144
constexpr int OFF_W3DT      = 194432;   // 7168
constexpr int OFF_W4T       = 201600;   // 2048
constexpr int OFF_YH        = 203648;   // 8388608 (y, later reused as H)
constexpr int OFF_X2P       = 8592256;  // 4194304

// scalar-by-value reduce: no array, no address-taken anywhere.
__device__ __forceinline__ void red1(float v, float* __restrict__ stats, int o, int sqoff) {
  float s = v, q = v * v;
  #pragma unroll
  for (int m = 32; m; m >>= 1) { s += __shfl_xor(s, m, 64); q += __shfl_xor(q, m, 64); }
  if ((threadIdx.x & 63) == 0) { atomicAdd(&stats[o], s); atomicAdd(&stats[sqoff + o], q); }
}

#define FMA4(A, W, X) { (A).x = fmaf((W).x, (X), (A).x); (A).y = fmaf((W).y, (X), (A).y); \
                        (A).z = fmaf((W).z, (X), (A).z); (A).w = fmaf((W).w, (X), (A).w); }
#define RELU4(A) { (A).x = fmaxf((A).x, 0.f); (A).y = fmaxf((A).y, 0.f); \
                   (A).z = fmaxf((A).z, 0.f); (A).w = fmaxf((A).w, 0.f); }
#define ZERO4(A) float4 A; (A).x = 0.f; (A).y = 0.f; (A).z = 0.f; (A).w = 0.f;

// ---------------- S0: setup ----------------
__global__ void s0_setup(const float* __restrict__ images, const float* __restrict__ offset1,
                         const float* __restrict__ w1, const float* __restrict__ w2,
                         const float* __restrict__ w3a, const float* __restrict__ w3b,
                         const float* __restrict__ w3c, const float* __restrict__ w3d,
                         const float* __restrict__ w4, float* __restrict__ ws)
{
  const int idx = blockIdx.x * blockDim.x + threadIdx.x;
  const int stride = gridDim.x * blockDim.x;
  for (int i = idx; i < 1280; i += stride) ws[i] = 0.f;
  for (int i = idx; i < 46656; i += stride) {
    int x = i % 36, t = i / 36, y = t % 36, z = t / 36;
    int xo = x - 2, yo = y - 2, zo = z - 2;
    float val = 0.f;
    if ((unsigned)xo < 32u && (unsigned)yo < 32u && (unsigned)zo < 32u)
      val = images[(zo * 32 + yo) * 32 + xo];
    ws[OFF_PVOL + i] = val;
  }
  for (int k = idx; k < 1024; k += stride) {
    int*   tpi = reinterpret_cast<int*>(ws + OFF_TPAR) + (k << 5);
    float* tpf = ws + OFF_TPAR + (k << 5);
    int dxi[2], dyi[2], dzi[2]; float wx0[2], wx1[2], zz[2][4];
    for (int s = 0; s < 2; ++s) {
      float ox = offset1[k * 6 + s * 3 + 0] * 16.f;
      float oy = offset1[k * 6 + s * 3 + 1] * 16.f;
      float oz = offset1[k * 6 + s * 3 + 2] * 16.f;
      ox = fminf(fmaxf(ox, -100.f), 100.f);
      oy = fminf(fmaxf(oy, -100.f), 100.f);
      oz = fminf(fmaxf(oz, -100.f), 100.f);
      float fxf = floorf(ox), fyf = floorf(oy), fzf = floorf(oz);
      float fx = ox - fxf, fy = oy - fyf, fz = oz - fzf;
      dxi[s] = (int)fxf + 2; dyi[s] = (int)fyf + 2; dzi[s] = (int)fzf + 2;
      wx0[s] = 1.f - fx; wx1[s] = fx;
      float wy0 = 1.f - fy, wy1 = fy, wz0 = 1.f - fz, wz1 = fz;
      float sgn = s ? -1.f : 1.f;
      zz[s][0] = sgn * wz0 * wy0; zz[s][1] = sgn * wz0 * wy1;
      zz[s][2] = sgn * wz1 * wy0; zz[s][3] = sgn * wz1 * wy1;
    }
    tpi[0] = dxi[0]; tpi[1] = dyi[0]; tpi[2] = dzi[0]; tpi[3] = dxi[1];
    tpi[4] = dyi[1]; tpi[5] = dzi[1]; tpi[6] = 0; tpi[7] = 0;
    tpf[8]  = wx0[0]; tpf[9]  = wx1[0]; tpf[10] = zz[0][0]; tpf[11] = zz[0][1];
    tpf[12] = zz[0][2]; tpf[13] = zz[0][3]; tpf[14] = wx0[1]; tpf[15] = wx1[1];
    tpf[16] = zz[1][0]; tpf[17] = zz[1][1]; tpf[18] = zz[1][2]; tpf[19] = zz[1][3];
  }
  for (int i = idx; i < 65536; i += stride) {
    int o = i & 63, t = i >> 6, c = t & 255, gg = t >> 8;
    ws[OFF_W1T + i] = w1[gg * 16384 + o * 256 + c];
  }
  for (int i = idx; i < 32768; i += stride) { int o = i & 127, c = i >> 7; ws[OFF_W2T + i] = w2[o * 256 + c]; }
  for (int i = idx; i < 4096;  i += stride) { int o = i & 31,  c = i >> 5; ws[OFF_W3AT + i] = w3a[o * 128 + c]; }
  for (int i = idx; i < 5120;  i += stride) { int o = i & 31,  c = i >> 5; ws[OFF_W3BT + i] = w3b[o * 160 + c]; }
  for (int i = idx; i < 6144;  i += stride) { int o = i & 31,  c = i >> 5; ws[OFF_W3CT + i] = w3c[o * 192 + c]; }
  for (int i = idx; i < 7168;  i += stride) { int o = i & 31,  c = i >> 5; ws[OFF_W3DT + i] = w3d[o * 224 + c]; }
  for (int i = idx; i < 2048;  i += stride) { int l = i & 7,   c = i >> 3; ws[OFF_W4T + i] = w4[l * 256 + c]; }
}

// ---------------- S1: fused gather + grouped GEMM (y = w1 @ x) ----------------
// 256 thr = 256 voxels; one group per blockIdx.y; 64 outputs in 16 named float4s.
__global__ __launch_bounds__(256) void s1_gather_gemm(
    const float* __restrict__ pvol, const int* __restrict__ tpar,
    const float* __restrict__ w1t, float* __restrict__ y, float* __restrict__ stats_y)
{
  const int tid = threadIdx.x;
  const int v = blockIdx.x * 256 + tid;
  const int g = blockIdx.y;
  const int xv = v & 31, yv = (v >> 5) & 31, zv = v >> 10;
  const int kbase = g << 8;

  ZERO4(a0) ZERO4(a1) ZERO4(a2) ZERO4(a3) ZERO4(a4) ZERO4(a5) ZERO4(a6) ZERO4(a7)
  ZERO4(a8) ZERO4(a9) ZERO4(a10) ZERO4(a11) ZERO4(a12) ZERO4(a13) ZERO4(a14) ZERO4(a15)

  #pragma unroll 1
  for (int k = 0; k < 256; ++k) {
    const int* tp = tpar + ((kbase + k) << 5);
    int4 ia = *(const int4*)(tp);
    int4 ib = *(const int4*)(tp + 4);
    float4 fa = *(const float4*)((const float*)tp + 8);
    float4 fb = *(const float4*)((const float*)tp + 12);
    float4 fc = *(const float4*)((const float*)tp + 16);
    float xval;
    {
      int xc = min(max(xv + ia.x, 0), 34);
      int yc = min(max(yv + ia.y, 0), 34);
      int zc = min(max(zv + ia.z, 0), 34);
      int r0 = (zc * 36 + yc) * 36 + xc;
      float v00 = pvol[r0],        v01 = pvol[r0 + 1];
      float v10 = pvol[r0 + 36],   v11 = pvol[r0 + 37];
      float v20 = pvol[r0 + 1296], v21 = pvol[r0 + 1297];
      float v30 = pvol[r0 + 1332], v31 = pvol[r0 + 1333];
      float h00 = v00 * fa.x + v01 * fa.y, h01 = v10 * fa.x + v11 * fa.y;
      float h10 = v20 * fa.x + v21 * fa.y, h11 = v30 * fa.x + v31 * fa.y;
      xval = fa.z * h00 + fa.w * h01 + fb.x * h10 + fb.y * h11;
    }
    {
      int xc = min(max(xv + ia.w, 0), 34);
      int yc = min(max(yv + ib.x, 0), 34);
      int zc = min(max(zv + ib.y, 0), 34);
      int r0 = (zc * 36 + yc) * 36 + xc;
      float v00 = pvol[r0],        v01 = pvol[r0 + 1];
      float v10 = pvol[r0 + 36],   v11 = pvol[r0 + 37];
      float v20 = pvol[r0 + 1296], v21 = pvol[r0 + 1297];
      float v30 = pvol[r0 + 1332], v31 = pvol[r0 + 1333];
      float h00 = v00 * fb.z + v01 * fb.w, h01 = v10 * fb.z + v11 * fb.w;
      float h10 = v20 * fb.z + v21 * fb.w, h11 = v30 * fb.z + v31 * fb.w;
      xval += fc.x * h00 + fc.y * h01 + fc.z * h10 + fc.w * h11; // fc pre-negated
    }
    const float4* wk = (const float4*)(w1t + ((size_t)(kbase + k) << 6));
    float4 w;
    w = wk[0];  FMA4(a0,  w, xval)
    w = wk[1];  FMA4(a1,  w, xval)
    w = wk[2];  FMA4(a2,  w, xval)
    w = wk[3];  FMA4(a3,  w, xval)
    w = wk[4];  FMA4(a4,  w, xval)
    w = wk[5];  FMA4(a5,  w, xval)
    w = wk[6];  FMA4(a6,  w, xval)
    w = wk[7];  FMA4(a7,  w, xval)
    w = wk[8];  FMA4(a8,  w, xval)
    w = wk[9];  FMA4(a9,  w, xval)
    w = wk[10]; FMA4(a10, w, xval)
    w = wk[11]; FMA4(a11, w, xval)
    w = wk[12]; FMA4(a12, w, xval)
    w = wk[13]; FMA4(a13, w, xval)
    w = wk[14]; FMA4(a14, w, xval)
    w = wk[15]; FMA4(a15, w, xval)
  }
  const int obase = g << 6;
  #define S1_OUT(A, o0) \
    y[((size_t)(obase + (o0) + 0)) * VOXN + v] = (A).x; \
    y[((size_t)(obase + (o0) + 1)) * VOXN + v] = (A).y; \
    y[((size_t)(obase + (o0) + 2)) * VOXN + v] = (A).z; \
    y[((size_t)(obase + (o0) + 3)) * VOXN + v] = (A).w; \
    red1((A).x, stats_y, obase + (o0) + 0, 256); \
    red1((A).y, stats_y, obase + (o0) + 1, 256); \
    red1((A).z, stats_y, obase + (o0) + 2, 256); \
    red1((A).w, stats_y, obase + (o0) + 3, 256);
  S1_OUT(a0, 0)  S1_OUT(a1, 4)  S1_OUT(a2, 8)   S1_OUT(a3, 12)
  S1_OUT(a4, 16) S1_OUT(a5, 20) S1_OUT(a6, 24)  S1_OUT(a7, 28)
  S1_OUT(a8, 32) S1_OUT(a9, 36) S1_OUT(a10, 40) S1_OUT(a11, 44)
  S1_OUT(a12, 48) S1_OUT(a13, 52) S1_OUT(a14, 56) S1_OUT(a15, 60)
  #undef S1_OUT
}

// ---------------- S2: x1 = relu(BN(y)); x2pre = w2 @ x1 (16 outputs/block) ----------------
__global__ __launch_bounds__(256) void s2_bn_gemm(
    const float* __restrict__ y, const float* __restrict__ stats_y,
    const float* __restrict__ g1, const float* __restrict__ b1,
    const float* __restrict__ w2t, float* __restrict__ x2p, float* __restrict__ stats_x2p)
{
  __shared__ float As[256], Bs[256];
  const int tid = threadIdx.x;
  {
    float m = stats_y[tid] * (1.f / VOXN);
    float vv = stats_y[256 + tid] * (1.f / VOXN) - m * m;
    float a = g1[tid] * rsqrtf(vv + 1e-5f);
    As[tid] = a; Bs[tid] = b1[tid] - m * a;
  }
  __syncthreads();
  const int q = blockIdx.y;            // 0..7
  const int n = blockIdx.x * 256 + tid;
  ZERO4(a0) ZERO4(a1) ZERO4(a2) ZERO4(a3)
  #pragma unroll 4
  for (int c = 0; c < 256; ++c) {
    float t = fmaxf(fmaf(y[(size_t)c * VOXN + n], As[c], Bs[c]), 0.f);
    const float4* wk = (const float4*)(w2t + c * 128 + q * 16);
    float4 w;
    w = wk[0]; FMA4(a0, w, t)
    w = wk[1]; FMA4(a1, w, t)
    w = wk[2]; FMA4(a2, w, t)
    w = wk[3]; FMA4(a3, w, t)
  }
  const int ob = q * 16;
  #define S2_OUT(A, o0) \
    x2p[((size_t)(ob + (o0) + 0)) * VOXN + n] = (A).x; \
    x2p[((size_t)(ob + (o0) + 1)) * VOXN + n] = (A).y; \
    x2p[((size_t)(ob + (o0) + 2)) * VOXN + n] = (A).z; \
    x2p[((size_t)(ob + (o0) + 3)) * VOXN + n] = (A).w; \
    red1((A).x, stats_x2p, ob + (o0) + 0, 128); \
    red1((A).y, stats_x2p, ob + (o0) + 1, 128); \
    red1((A).z, stats_x2p, ob + (o0) + 2, 128); \
    red1((A).w, stats_x2p, ob + (o0) + 3, 128);
  S2_OUT(a0, 0) S2_OUT(a1, 4) S2_OUT(a2, 8) S2_OUT(a3, 12)
  #undef S2_OUT
}

// ---------------- S3: x2 = BN(x2pre) -> H[0:128]; ha = relu(w3a@x2) -> H[128+half*16 ..] ----------------
__global__ __launch_bounds__(256) void s3_x2_ha(
    const float* __restrict__ x2p, const float* __restrict__ stats_x2p,
    const float* __restrict__ g2, const float* __restrict__ b2,
    const float* __restrict__ w3at, float* __restrict__ H, float* __restrict__ stats_H)
{
  __shared__ float As[128], Bs[128];
  const int tid = threadIdx.x;
  if (tid < 128) {
    float m = stats_x2p[tid] * (1.f / VOXN);
    float vv = stats_x2p[128 + tid] * (1.f / VOXN) - m * m;
    float a = g2[tid] * rsqrtf(vv + 1e-5f);
    As[tid] = a; Bs[tid] = b2[tid] - m * a;
    if (blockIdx.x == 0 && blockIdx.y == 0) {
      float mean = b2[tid];
      float var = a * a * vv;
      stats_H[tid] = mean * (float)VOXN;
      stats_H[256 + tid] = (var + mean * mean) * (float)VOXN;
    }
  }
  __syncthreads();
  const int half = blockIdx.y;         // 0..1
  const int n = blockIdx.x * 256 + tid;
  ZERO4(a0) ZERO4(a1) ZERO4(a2) ZERO4(a3)
  #pragma unroll 4
  for (int c = 0; c < 128; ++c) {
    float x2v = fmaf(x2p[(size_t)c * VOXN + n], As[c], Bs[c]);
    if (half == 0) H[(size_t)c * VOXN + n] = x2v;
    const float4* wk = (const float4*)(w3at + c * 32 + half * 16);
    float4 w;
    w = wk[0]; FMA4(a0, w, x2v)
    w = wk[1]; FMA4(a1, w, x2v)
    w = wk[2]; FMA4(a2, w, x2v)
    w = wk[3]; FMA4(a3, w, x2v)
  }
  RELU4(a0) RELU4(a1) RELU4(a2) RELU4(a3)
  const int ob = 128 + half * 16;
  #define S3_OUT(A, o0) \
    H[((size_t)(ob + (o0) + 0)) * VOXN + n] = (A).x; \
    H[((size_t)(ob + (o0) + 1)) * VOXN + n] = (A).y; \
    H[((size_t)(ob + (o0) + 2)) * VOXN + n] = (A).z; \
    H[((size_t)(ob + (o0) + 3)) * VOXN + n] = (A).w; \
    red1((A).x, stats_H, ob + (o0) + 0, 256); \
    red1((A).y, stats_H, ob + (o0) + 1, 256); \
    red1((A).z, stats_H, ob + (o0) + 2, 256); \
    red1((A).w, stats_H, ob + (o0) + 3, 256);
  S3_OUT(a0, 0) S3_OUT(a1, 4) S3_OUT(a2, 8) S3_OUT(a3, 12)
  #undef S3_OUT
}

// ---------------- S4/5/6: h = relu(w @ BN(H[0:CIN])) -> H[och + half*16 ..] ----------------
template<int CIN>
__global__ __launch_bounds__(256) void s_dense(
    const float* __restrict__ Hin, const float* __restrict__ stats_H,
    const float* __restrict__ g, const float* __restrict__ b,
    const float* __restrict__ wt, float* __restrict__ H, float* __restrict__ stats_out, int och)
{
  __shared__ float As[CIN], Bs[CIN];
  const int tid = threadIdx.x;
  if (tid < CIN) {
    float m = stats_H[tid] * (1.f / VOXN);
    float vv = stats_H[256 + tid] * (1.f / VOXN) - m * m;
    float a = g[tid] * rsqrtf(vv + 1e-5f);
    As[tid] = a; Bs[tid] = b[tid] - m * a;
  }
  __syncthreads();
  const int osub = blockIdx.y * 16;
  const int n = blockIdx.x * 256 + tid;
  ZERO4(a0) ZERO4(a1) ZERO4(a2) ZERO4(a3)
  #pragma unroll 4
  for (int c = 0; c < CIN; ++c) {
    float t = fmaf(Hin[(size_t)c * VOXN + n], As[c], Bs[c]);
    const float4* wk = (const float4*)(wt + c * 32 + osub);
    float4 w;
    w = wk[0]; FMA4(a0, w, t)
    w = wk[1]; FMA4(a1, w, t)
    w = wk[2]; FMA4(a2, w, t)
    w = wk[3]; FMA4(a3, w, t)
  }
  RELU4(a0) RELU4(a1) RELU4(a2) RELU4(a3)
  const int ob = och + osub;
  #define SD_OUT(A, o0) \
    H[((size_t)(ob + (o0) + 0)) * VOXN + n] = (A).x; \
    H[((size_t)(ob + (o0) + 1)) * VOXN + n] = (A).y; \
    H[((size_t)(ob + (o0) + 2)) * VOXN + n] = (A).z; \
    H[((size_t)(ob + (o0) + 3)) * VOXN + n] = (A).w; \
    red1((A).x, stats_out, ob + (o0) + 0, 256); \
    red1((A).y, stats_out, ob + (o0) + 1, 256); \
    red1((A).z, stats_out, ob + (o0) + 2, 256); \
    red1((A).w, stats_out, ob + (o0) + 3, 256);
  SD_OUT(a0, 0) SD_OUT(a1, 4) SD_OUT(a2, 8) SD_OUT(a3, 12)
  #undef SD_OUT
}

// ---------------- S7: out = sigmoid(w4 @ BN(H) + b4) ----------------
__global__ __launch_bounds__(256) void s7_final(
    const float* __restrict__ H, const float* __restrict__ stats_H,
    const float* __restrict__ g3d, const float* __restrict__ b3d,
    const float* __restrict__ w4t, const float* __restrict__ b4, float* __restrict__ out)
{
  __shared__ float As[256], Bs[256];
  const int tid = threadIdx.x;
  {
    float m = stats_H[tid] * (1.f / VOXN);
    float vv = stats_H[256 + tid] * (1.f / VOXN) - m * m;
    float a = g3d[tid] * rsqrtf(vv + 1e-5f);
    As[tid] = a; Bs[tid] = b3d[tid] - m * a;
  }
  __syncthreads();
  const int n = blockIdx.x * 256 + tid;
  ZERO4(a0) ZERO4(a1)
  #pragma unroll 4
  for (int c = 0; c < 256; ++c) {
    float t = fmaf(H[(size_t)c * VOXN + n], As[c], Bs[c]);
    const float4* wk = (const float4*)(w4t + c * 8);
    float4 w;
    w = wk[0]; FMA4(a0, w, t)
    w = wk[1]; FMA4(a1, w, t)
  }
  out[(size_t)0 * VOXN + n] = 1.f / (1.f + expf(-(a0.x + b4[0])));
  out[(size_t)1 * VOXN + n] = 1.f / (1.f + expf(-(a0.y + b4[1])));
  out[(size_t)2 * VOXN + n] = 1.f / (1.f + expf(-(a0.z + b4[2])));
  out[(size_t)3 * VOXN + n] = 1.f / (1.f + expf(-(a0.w + b4[3])));
  out[(size_t)4 * VOXN + n] = 1.f / (1.f + expf(-(a1.x + b4[4])));
  out[(size_t)5 * VOXN + n] = 1.f / (1.f + expf(-(a1.y + b4[5])));
  out[(size_t)6 * VOXN + n] = 1.f / (1.f + expf(-(a1.z + b4[6])));
  out[(size_t)7 * VOXN + n] = 1.f / (1.f + expf(-(a1.w + b4[7])));
}

extern "C" void kernel_launch(void* const* d_in, const int* in_sizes, int n_in,
                              void* d_out, int out_size, void* d_ws, size_t ws_size,
                              hipStream_t stream)
{
  const float* images  = (const float*)d_in[0];
  const float* offset1 = (const float*)d_in[1];
  const float* w1  = (const float*)d_in[2];
  const float* g1  = (const float*)d_in[3];
  const float* b1  = (const float*)d_in[4];
  const float* w2  = (const float*)d_in[5];
  const float* g2  = (const float*)d_in[6];
  const float* b2  = (const float*)d_in[7];
  const float* w3a = (const float*)d_in[8];
  const float* w3b = (const float*)d_in[9];
  const float* w3c = (const float*)d_in[10];
  const float* w3d = (const float*)d_in[11];
  const float* g3a = (const float*)d_in[12];
  const float* b3a = (const float*)d_in[13];
  const float* g3b = (const float*)d_in[14];
  const float* b3b = (const float*)d_in[15];
  const float* g3c = (const float*)d_in[16];
  const float* b3c = (const float*)d_in[17];
  const float* g3d = (const float*)d_in[18];
  const float* b3d = (const float*)d_in[19];
  const float* w4  = (const float*)d_in[20];
  const float* b4  = (const float*)d_in[21];

  float* ws  = (float*)d_ws;
  float* out = (float*)d_out;

  float* statsY = ws + OFF_STATS_Y;
  float* statsX = ws + OFF_STATS_X2P;
  float* statsH = ws + OFF_STATS_H;
  float* pvol   = ws + OFF_PVOL;
  float* w1t    = ws + OFF_W1T;
  float* w2t    = ws + OFF_W2T;
  float* YH     = ws + OFF_YH;   // y, later H
  float* x2p    = ws + OFF_X2P;

  s0_setup<<<dim3(64), dim3(256), 0, stream>>>(images, offset1, w1, w2, w3a, w3b, w3c, w3d, w4, ws);
  s1_gather_gemm<<<dim3(128, 4), dim3(256), 0, stream>>>(pvol, (const int*)(ws + OFF_TPAR), w1t, YH, statsY);
  s2_bn_gemm<<<dim3(128, 8), dim3(256), 0, stream>>>(YH, statsY, g1, b1, w2t, x2p, statsX);
  s3_x2_ha<<<dim3(128, 2), dim3(256), 0, stream>>>(x2p, statsX, g2, b2, ws + OFF_W3AT, YH, statsH);
  s_dense<160><<<dim3(128, 2), dim3(256), 0, stream>>>(YH, statsH, g3a, b3a, ws + OFF_W3BT, YH, statsH, 160);
  s_dense<192><<<dim3(128, 2), dim3(256), 0, stream>>>(YH, statsH, g3b, b3b, ws + OFF_W3CT, YH, statsH, 192);
  s_dense<224><<<dim3(128, 2), dim3(256), 0, stream>>>(YH, statsH, g3c, b3c, ws + OFF_W3DT, YH, statsH, 224);
  s7_final<<<dim3(128), dim3(256), 0, stream>>>(YH, statsH, g3d, b3d, ws + OFF_W4T, b4, out);
}

// Round 5
// 569.004 us; speedup vs baseline: 3.0224x; 2.4985x over previous
//
#include <hip/hip_runtime.h>
#include <math.h>

#define VOXN 32768

// ---- workspace layout (float offsets) ----
constexpr int OFF_STATS_Y   = 0;        // 512
constexpr int OFF_STATS_X2P = 512;      // 256
constexpr int OFF_STATS_H   = 768;      // 512
constexpr int OFF_TPAR      = 1280;     // 1024*16 packed tap params
constexpr int OFF_W1T       = 17664;    // 65536
constexpr int OFF_W2T       = 83200;    // 32768
constexpr int OFF_W3AT      = 115968;   // 4096
constexpr int OFF_W3BT      = 120064;   // 5120
constexpr int OFF_W3CT      = 125184;   // 6144
constexpr int OFF_W3DT      = 131328;   // 7168
constexpr int OFF_W4T       = 138496;   // 2048
constexpr int OFF_YH        = 140544;   // 8388608 (y, later H)
constexpr int OFF_X2P       = 8529152;  // 4194304 (x2pre; ALSO hosts pvol98 early)
constexpr int OFF_PVOL      = OFF_X2P;  // 941192 floats (98^3), dead before s2 writes x2p

#define FMA4(A, W, X) { (A).x = fmaf((W).x, (X), (A).x); (A).y = fmaf((W).y, (X), (A).y); \
                        (A).z = fmaf((W).z, (X), (A).z); (A).w = fmaf((W).w, (X), (A).w); }
#define RELU4(A) { (A).x = fmaxf((A).x, 0.f); (A).y = fmaxf((A).y, 0.f); \
                   (A).z = fmaxf((A).z, 0.f); (A).w = fmaxf((A).w, 0.f); }
#define ZERO4(A) float4 A; (A).x = 0.f; (A).y = 0.f; (A).z = 0.f; (A).w = 0.f;

// butterfly reduce (s,q) across 64 lanes — fully unrolled, scalar regs only
#define BFLY(s, q) { s += __shfl_xor(s, 32, 64); q += __shfl_xor(q, 32, 64); \
                     s += __shfl_xor(s, 16, 64); q += __shfl_xor(q, 16, 64); \
                     s += __shfl_xor(s,  8, 64); q += __shfl_xor(q,  8, 64); \
                     s += __shfl_xor(s,  4, 64); q += __shfl_xor(q,  4, 64); \
                     s += __shfl_xor(s,  2, 64); q += __shfl_xor(q,  2, 64); \
                     s += __shfl_xor(s,  1, 64); q += __shfl_xor(q,  1, 64); }
// lane == o keeps channel o's block-wave partial in (ms,mq)
#define STASH1(V, O) { float s_ = (V), q_ = (V) * (V); BFLY(s_, q_) \
                       if (lane == (O)) { ms = s_; mq = q_; } }
#define STASH4(A, O0) STASH1((A).x, (O0)+0) STASH1((A).y, (O0)+1) \
                      STASH1((A).z, (O0)+2) STASH1((A).w, (O0)+3)

// ---------------- S0: setup ----------------
__global__ void s0_setup(const float* __restrict__ images, const float* __restrict__ offset1,
                         const float* __restrict__ w1, const float* __restrict__ w2,
                         const float* __restrict__ w3a, const float* __restrict__ w3b,
                         const float* __restrict__ w3c, const float* __restrict__ w3d,
                         const float* __restrict__ w4, float* __restrict__ ws)
{
  const int idx = blockIdx.x * blockDim.x + threadIdx.x;
  const int stride = gridDim.x * blockDim.x;
  for (int i = idx; i < 1280; i += stride) ws[i] = 0.f;
  // padded volume 98^3: interior [33,64] = images, else 0
  float* pvol = ws + OFF_PVOL;
  for (int i = idx; i < 941192; i += stride) {
    int x = i % 98, t = i / 98, y = t % 98, z = t / 98;
    float val = 0.f;
    if (x >= 33 && x < 65 && y >= 33 && y < 65 && z >= 33 && z < 65)
      val = images[((z - 33) * 32 + (y - 33)) * 32 + (x - 33)];
    pvol[i] = val;
  }
  // packed tap params: per k 16 floats: [c0i,wx0,wx1,zz0,zz1,zz2,zz3,0] x 2 taps (tap b negated)
  for (int k = idx; k < 1024; k += stride) {
    float* tp = ws + OFF_TPAR + k * 16;
    for (int s = 0; s < 2; ++s) {
      float ox = fminf(fmaxf(offset1[k * 6 + s * 3 + 0] * 16.f, -1000.f), 1000.f);
      float oy = fminf(fmaxf(offset1[k * 6 + s * 3 + 1] * 16.f, -1000.f), 1000.f);
      float oz = fminf(fmaxf(offset1[k * 6 + s * 3 + 2] * 16.f, -1000.f), 1000.f);
      float fxf = floorf(ox), fyf = floorf(oy), fzf = floorf(oz);
      float fx = ox - fxf, fy = oy - fyf, fz = oz - fzf;
      int sx = (int)fxf, sy = (int)fyf, sz = (int)fzf;
      bool valid = (sx >= -33 && sx <= 32) && (sy >= -33 && sy <= 32) && (sz >= -33 && sz <= 32);
      if (!valid) { sx = sy = sz = 0; }
      float vm = valid ? 1.f : 0.f;
      int c0 = (sz + 33) * 9604 + (sy + 33) * 98 + (sx + 33);
      float sgn = s ? -1.f : 1.f;
      float wy0 = 1.f - fy, wy1 = fy, wz0 = 1.f - fz, wz1 = fz;
      tp[s * 8 + 0] = __int_as_float(c0);
      tp[s * 8 + 1] = vm * (1.f - fx);
      tp[s * 8 + 2] = vm * fx;
      tp[s * 8 + 3] = vm * sgn * wz0 * wy0;
      tp[s * 8 + 4] = vm * sgn * wz0 * wy1;
      tp[s * 8 + 5] = vm * sgn * wz1 * wy0;
      tp[s * 8 + 6] = vm * sgn * wz1 * wy1;
      tp[s * 8 + 7] = 0.f;
    }
  }
  for (int i = idx; i < 65536; i += stride) {
    int o = i & 63, t = i >> 6, c = t & 255, gg = t >> 8;
    ws[OFF_W1T + i] = w1[gg * 16384 + o * 256 + c];
  }
  for (int i = idx; i < 32768; i += stride) { int o = i & 127, c = i >> 7; ws[OFF_W2T + i] = w2[o * 256 + c]; }
  for (int i = idx; i < 4096;  i += stride) { int o = i & 31,  c = i >> 5; ws[OFF_W3AT + i] = w3a[o * 128 + c]; }
  for (int i = idx; i < 5120;  i += stride) { int o = i & 31,  c = i >> 5; ws[OFF_W3BT + i] = w3b[o * 160 + c]; }
  for (int i = idx; i < 6144;  i += stride) { int o = i & 31,  c = i >> 5; ws[OFF_W3CT + i] = w3c[o * 192 + c]; }
  for (int i = idx; i < 7168;  i += stride) { int o = i & 31,  c = i >> 5; ws[OFF_W3DT + i] = w3d[o * 224 + c]; }
  for (int i = idx; i < 2048;  i += stride) { int l = i & 7,   c = i >> 3; ws[OFF_W4T + i] = w4[l * 256 + c]; }
}

// ---------------- S1: fused gather + grouped GEMM ----------------
// 256 thr = 256 voxels, one group per blockIdx.y. Weights + tap params in LDS.
// No clamps: 98^3 padded volume makes every tap address vbase + const_k.
__global__ __launch_bounds__(256) void s1_gather_gemm(
    const float* __restrict__ pvol, const float* __restrict__ tpar,
    const float* __restrict__ w1t, float* __restrict__ y, float* __restrict__ stats_y)
{
  __shared__ float wlds[128 * 64];    // 32 KB: half-K weight tile
  __shared__ float tplds[256 * 16];   // 16 KB: all tap params for this group
  __shared__ float redS[4][64], redQ[4][64];
  const int tid = threadIdx.x;
  const int lane = tid & 63;
  const int wv = tid >> 6;
  const int g = blockIdx.y;
  const int v = blockIdx.x * 256 + tid;
  const int vbase = (v >> 10) * 9604 + ((v >> 5) & 31) * 98 + (v & 31);

  { // stage tap params (1024 float4s)
    const float4* src = (const float4*)(tpar + g * 4096);
    float4* dst = (float4*)tplds;
    #pragma unroll
    for (int j = 0; j < 4; ++j) dst[tid + j * 256] = src[tid + j * 256];
  }

  ZERO4(a0) ZERO4(a1) ZERO4(a2) ZERO4(a3) ZERO4(a4) ZERO4(a5) ZERO4(a6) ZERO4(a7)
  ZERO4(a8) ZERO4(a9) ZERO4(a10) ZERO4(a11) ZERO4(a12) ZERO4(a13) ZERO4(a14) ZERO4(a15)

  for (int half = 0; half < 2; ++half) {
    __syncthreads();
    { // stage weights for this K-half (2048 float4s)
      const float4* src = (const float4*)(w1t + (g * 256 + half * 128) * 64);
      float4* dst = (float4*)wlds;
      #pragma unroll
      for (int j = 0; j < 8; ++j) dst[tid + j * 256] = src[tid + j * 256];
    }
    __syncthreads();
    #pragma unroll 1
    for (int kk = 0; kk < 128; ++kk) {
      const int kt = half * 128 + kk;
      float4 t0 = *(const float4*)&tplds[kt * 16];
      float4 t1 = *(const float4*)&tplds[kt * 16 + 4];
      float4 t2 = *(const float4*)&tplds[kt * 16 + 8];
      float4 t3 = *(const float4*)&tplds[kt * 16 + 12];
      float xval;
      {
        const float* p = pvol + (vbase + __float_as_int(t0.x));
        float h0 = p[0]    * t0.y + p[1]    * t0.z;
        float h1 = p[98]   * t0.y + p[99]   * t0.z;
        float h2 = p[9604] * t0.y + p[9605] * t0.z;
        float h3 = p[9702] * t0.y + p[9703] * t0.z;
        xval = h0 * t0.w + h1 * t1.x + h2 * t1.y + h3 * t1.z;
      }
      {
        const float* p = pvol + (vbase + __float_as_int(t2.x));
        float h0 = p[0]    * t2.y + p[1]    * t2.z;
        float h1 = p[98]   * t2.y + p[99]   * t2.z;
        float h2 = p[9604] * t2.y + p[9605] * t2.z;
        float h3 = p[9702] * t2.y + p[9703] * t2.z;
        xval += h0 * t2.w + h1 * t3.x + h2 * t3.y + h3 * t3.z; // tap b pre-negated
      }
      const float4* wk = (const float4*)&wlds[kk * 64];
      float4 w;
      w = wk[0];  FMA4(a0,  w, xval)
      w = wk[1];  FMA4(a1,  w, xval)
      w = wk[2];  FMA4(a2,  w, xval)
      w = wk[3];  FMA4(a3,  w, xval)
      w = wk[4];  FMA4(a4,  w, xval)
      w = wk[5];  FMA4(a5,  w, xval)
      w = wk[6];  FMA4(a6,  w, xval)
      w = wk[7];  FMA4(a7,  w, xval)
      w = wk[8];  FMA4(a8,  w, xval)
      w = wk[9];  FMA4(a9,  w, xval)
      w = wk[10]; FMA4(a10, w, xval)
      w = wk[11]; FMA4(a11, w, xval)
      w = wk[12]; FMA4(a12, w, xval)
      w = wk[13]; FMA4(a13, w, xval)
      w = wk[14]; FMA4(a14, w, xval)
      w = wk[15]; FMA4(a15, w, xval)
    }
  }
  const int obase = g << 6;
  #define S1_ST(A, o0) \
    y[((size_t)(obase + (o0) + 0)) * VOXN + v] = (A).x; \
    y[((size_t)(obase + (o0) + 1)) * VOXN + v] = (A).y; \
    y[((size_t)(obase + (o0) + 2)) * VOXN + v] = (A).z; \
    y[((size_t)(obase + (o0) + 3)) * VOXN + v] = (A).w;
  S1_ST(a0, 0)   S1_ST(a1, 4)   S1_ST(a2, 8)   S1_ST(a3, 12)
  S1_ST(a4, 16)  S1_ST(a5, 20)  S1_ST(a6, 24)  S1_ST(a7, 28)
  S1_ST(a8, 32)  S1_ST(a9, 36)  S1_ST(a10, 40) S1_ST(a11, 44)
  S1_ST(a12, 48) S1_ST(a13, 52) S1_ST(a14, 56) S1_ST(a15, 60)
  #undef S1_ST
  float ms = 0.f, mq = 0.f;
  STASH4(a0, 0)   STASH4(a1, 4)   STASH4(a2, 8)   STASH4(a3, 12)
  STASH4(a4, 16)  STASH4(a5, 20)  STASH4(a6, 24)  STASH4(a7, 28)
  STASH4(a8, 32)  STASH4(a9, 36)  STASH4(a10, 40) STASH4(a11, 44)
  STASH4(a12, 48) STASH4(a13, 52) STASH4(a14, 56) STASH4(a15, 60)
  redS[wv][lane] = ms; redQ[wv][lane] = mq;
  __syncthreads();
  if (tid < 64) {
    float s = redS[0][tid] + redS[1][tid] + redS[2][tid] + redS[3][tid];
    float q = redQ[0][tid] + redQ[1][tid] + redQ[2][tid] + redQ[3][tid];
    atomicAdd(&stats_y[obase + tid], s);
    atomicAdd(&stats_y[256 + obase + tid], q);
  }
}

// ---------------- S2: x1 = relu(BN(y)); x2pre = w2 @ x1 (32 outputs/block) ----------------
__global__ __launch_bounds__(256) void s2_bn_gemm(
    const float* __restrict__ y, const float* __restrict__ stats_y,
    const float* __restrict__ g1, const float* __restrict__ b1,
    const float* __restrict__ w2t, float* __restrict__ x2p, float* __restrict__ stats_x2p)
{
  __shared__ float As[256], Bs[256];
  __shared__ float redS[4][32], redQ[4][32];
  const int tid = threadIdx.x;
  const int lane = tid & 63;
  const int wv = tid >> 6;
  {
    float m = stats_y[tid] * (1.f / VOXN);
    float vv = stats_y[256 + tid] * (1.f / VOXN) - m * m;
    float a = g1[tid] * rsqrtf(vv + 1e-5f);
    As[tid] = a; Bs[tid] = b1[tid] - m * a;
  }
  __syncthreads();
  const int q = blockIdx.y;            // 0..3 -> outputs q*32..+31
  const int n = blockIdx.x * 256 + tid;
  ZERO4(a0) ZERO4(a1) ZERO4(a2) ZERO4(a3) ZERO4(a4) ZERO4(a5) ZERO4(a6) ZERO4(a7)
  #pragma unroll 4
  for (int c = 0; c < 256; ++c) {
    float t = fmaxf(fmaf(y[(size_t)c * VOXN + n], As[c], Bs[c]), 0.f);
    const float4* wk = (const float4*)(w2t + c * 128 + q * 32);
    float4 w;
    w = wk[0]; FMA4(a0, w, t)
    w = wk[1]; FMA4(a1, w, t)
    w = wk[2]; FMA4(a2, w, t)
    w = wk[3]; FMA4(a3, w, t)
    w = wk[4]; FMA4(a4, w, t)
    w = wk[5]; FMA4(a5, w, t)
    w = wk[6]; FMA4(a6, w, t)
    w = wk[7]; FMA4(a7, w, t)
  }
  const int ob = q * 32;
  #define S2_ST(A, o0) \
    x2p[((size_t)(ob + (o0) + 0)) * VOXN + n] = (A).x; \
    x2p[((size_t)(ob + (o0) + 1)) * VOXN + n] = (A).y; \
    x2p[((size_t)(ob + (o0) + 2)) * VOXN + n] = (A).z; \
    x2p[((size_t)(ob + (o0) + 3)) * VOXN + n] = (A).w;
  S2_ST(a0, 0) S2_ST(a1, 4) S2_ST(a2, 8) S2_ST(a3, 12)
  S2_ST(a4, 16) S2_ST(a5, 20) S2_ST(a6, 24) S2_ST(a7, 28)
  #undef S2_ST
  float ms = 0.f, mq = 0.f;
  STASH4(a0, 0) STASH4(a1, 4) STASH4(a2, 8) STASH4(a3, 12)
  STASH4(a4, 16) STASH4(a5, 20) STASH4(a6, 24) STASH4(a7, 28)
  if (lane < 32) { redS[wv][lane] = ms; redQ[wv][lane] = mq; }
  __syncthreads();
  if (tid < 32) {
    float s = redS[0][tid] + redS[1][tid] + redS[2][tid] + redS[3][tid];
    float qq = redQ[0][tid] + redQ[1][tid] + redQ[2][tid] + redQ[3][tid];
    atomicAdd(&stats_x2p[ob + tid], s);
    atomicAdd(&stats_x2p[128 + ob + tid], qq);
  }
}

// ---------------- S3: x2 = BN(x2pre) -> H[0:128]; ha = relu(w3a@x2) -> H[128+half*16 ..] ----------------
__global__ __launch_bounds__(256) void s3_x2_ha(
    const float* __restrict__ x2p, const float* __restrict__ stats_x2p,
    const float* __restrict__ g2, const float* __restrict__ b2,
    const float* __restrict__ w3at, float* __restrict__ H, float* __restrict__ stats_H)
{
  __shared__ float As[128], Bs[128];
  __shared__ float redS[4][16], redQ[4][16];
  const int tid = threadIdx.x;
  const int lane = tid & 63;
  const int wv = tid >> 6;
  if (tid < 128) {
    float m = stats_x2p[tid] * (1.f / VOXN);
    float vv = stats_x2p[128 + tid] * (1.f / VOXN) - m * m;
    float a = g2[tid] * rsqrtf(vv + 1e-5f);
    As[tid] = a; Bs[tid] = b2[tid] - m * a;
    if (blockIdx.x == 0 && blockIdx.y == 0) {
      float mean = b2[tid];
      float var = a * a * vv;
      stats_H[tid] = mean * (float)VOXN;
      stats_H[256 + tid] = (var + mean * mean) * (float)VOXN;
    }
  }
  __syncthreads();
  const int half = blockIdx.y;
  const int n = blockIdx.x * 256 + tid;
  ZERO4(a0) ZERO4(a1) ZERO4(a2) ZERO4(a3)
  #pragma unroll 4
  for (int c = 0; c < 128; ++c) {
    float x2v = fmaf(x2p[(size_t)c * VOXN + n], As[c], Bs[c]);
    if (half == 0) H[(size_t)c * VOXN + n] = x2v;
    const float4* wk = (const float4*)(w3at + c * 32 + half * 16);
    float4 w;
    w = wk[0]; FMA4(a0, w, x2v)
    w = wk[1]; FMA4(a1, w, x2v)
    w = wk[2]; FMA4(a2, w, x2v)
    w = wk[3]; FMA4(a3, w, x2v)
  }
  RELU4(a0) RELU4(a1) RELU4(a2) RELU4(a3)
  const int ob = 128 + half * 16;
  #define S3_ST(A, o0) \
    H[((size_t)(ob + (o0) + 0)) * VOXN + n] = (A).x; \
    H[((size_t)(ob + (o0) + 1)) * VOXN + n] = (A).y; \
    H[((size_t)(ob + (o0) + 2)) * VOXN + n] = (A).z; \
    H[((size_t)(ob + (o0) + 3)) * VOXN + n] = (A).w;
  S3_ST(a0, 0) S3_ST(a1, 4) S3_ST(a2, 8) S3_ST(a3, 12)
  #undef S3_ST
  float ms = 0.f, mq = 0.f;
  STASH4(a0, 0) STASH4(a1, 4) STASH4(a2, 8) STASH4(a3, 12)
  if (lane < 16) { redS[wv][lane] = ms; redQ[wv][lane] = mq; }
  __syncthreads();
  if (tid < 16) {
    float s = redS[0][tid] + redS[1][tid] + redS[2][tid] + redS[3][tid];
    float qq = redQ[0][tid] + redQ[1][tid] + redQ[2][tid] + redQ[3][tid];
    atomicAdd(&stats_H[ob + tid], s);
    atomicAdd(&stats_H[256 + ob + tid], qq);
  }
}

// ---------------- S4/5/6: h = relu(w @ BN(H[0:CIN])) -> H[och + osub ..] ----------------
template<int CIN>
__global__ __launch_bounds__(256) void s_dense(
    const float* __restrict__ Hin, const float* __restrict__ stats_H,
    const float* __restrict__ g, const float* __restrict__ b,
    const float* __restrict__ wt, float* __restrict__ H, float* __restrict__ stats_out, int och)
{
  __shared__ float As[CIN], Bs[CIN];
  __shared__ float redS[4][16], redQ[4][16];
  const int tid = threadIdx.x;
  const int lane = tid & 63;
  const int wv = tid >> 6;
  if (tid < CIN) {
    float m = stats_H[tid] * (1.f / VOXN);
    float vv = stats_H[256 + tid] * (1.f / VOXN) - m * m;
    float a = g[tid] * rsqrtf(vv + 1e-5f);
    As[tid] = a; Bs[tid] = b[tid] - m * a;
  }
  __syncthreads();
  const int osub = blockIdx.y * 16;
  const int n = blockIdx.x * 256 + tid;
  ZERO4(a0) ZERO4(a1) ZERO4(a2) ZERO4(a3)
  #pragma unroll 4
  for (int c = 0; c < CIN; ++c) {
    float t = fmaf(Hin[(size_t)c * VOXN + n], As[c], Bs[c]);
    const float4* wk = (const float4*)(wt + c * 32 + osub);
    float4 w;
    w = wk[0]; FMA4(a0, w, t)
    w = wk[1]; FMA4(a1, w, t)
    w = wk[2]; FMA4(a2, w, t)
    w = wk[3]; FMA4(a3, w, t)
  }
  RELU4(a0) RELU4(a1) RELU4(a2) RELU4(a3)
  const int ob = och + osub;
  #define SD_ST(A, o0) \
    H[((size_t)(ob + (o0) + 0)) * VOXN + n] = (A).x; \
    H[((size_t)(ob + (o0) + 1)) * VOXN + n] = (A).y; \
    H[((size_t)(ob + (o0) + 2)) * VOXN + n] = (A).z; \
    H[((size_t)(ob + (o0) + 3)) * VOXN + n] = (A).w;
  SD_ST(a0, 0) SD_ST(a1, 4) SD_ST(a2, 8) SD_ST(a3, 12)
  #undef SD_ST
  float ms = 0.f, mq = 0.f;
  STASH4(a0, 0) STASH4(a1, 4) STASH4(a2, 8) STASH4(a3, 12)
  if (lane < 16) { redS[wv][lane] = ms; redQ[wv][lane] = mq; }
  __syncthreads();
  if (tid < 16) {
    float s = redS[0][tid] + redS[1][tid] + redS[2][tid] + redS[3][tid];
    float qq = redQ[0][tid] + redQ[1][tid] + redQ[2][tid] + redQ[3][tid];
    atomicAdd(&stats_out[ob + tid], s);
    atomicAdd(&stats_out[256 + ob + tid], qq);
  }
}

// ---------------- S7: out = sigmoid(w4 @ BN(H) + b4) ----------------
__global__ __launch_bounds__(256) void s7_final(
    const float* __restrict__ H, const float* __restrict__ stats_H,
    const float* __restrict__ g3d, const float* __restrict__ b3d,
    const float* __restrict__ w4t, const float* __restrict__ b4, float* __restrict__ out)
{
  __shared__ float As[256], Bs[256];
  const int tid = threadIdx.x;
  {
    float m = stats_H[tid] * (1.f / VOXN);
    float vv = stats_H[256 + tid] * (1.f / VOXN) - m * m;
    float a = g3d[tid] * rsqrtf(vv + 1e-5f);
    As[tid] = a; Bs[tid] = b3d[tid] - m * a;
  }
  __syncthreads();
  const int n = blockIdx.x * 256 + tid;
  ZERO4(a0) ZERO4(a1)
  #pragma unroll 4
  for (int c = 0; c < 256; ++c) {
    float t = fmaf(H[(size_t)c * VOXN + n], As[c], Bs[c]);
    const float4* wk = (const float4*)(w4t + c * 8);
    float4 w;
    w = wk[0]; FMA4(a0, w, t)
    w = wk[1]; FMA4(a1, w, t)
  }
  out[(size_t)0 * VOXN + n] = 1.f / (1.f + expf(-(a0.x + b4[0])));
  out[(size_t)1 * VOXN + n] = 1.f / (1.f + expf(-(a0.y + b4[1])));
  out[(size_t)2 * VOXN + n] = 1.f / (1.f + expf(-(a0.z + b4[2])));
  out[(size_t)3 * VOXN + n] = 1.f / (1.f + expf(-(a0.w + b4[3])));
  out[(size_t)4 * VOXN + n] = 1.f / (1.f + expf(-(a1.x + b4[4])));
  out[(size_t)5 * VOXN + n] = 1.f / (1.f + expf(-(a1.y + b4[5])));
  out[(size_t)6 * VOXN + n] = 1.f / (1.f + expf(-(a1.z + b4[6])));
  out[(size_t)7 * VOXN + n] = 1.f / (1.f + expf(-(a1.w + b4[7])));
}

extern "C" void kernel_launch(void* const* d_in, const int* in_sizes, int n_in,
                              void* d_out, int out_size, void* d_ws, size_t ws_size,
                              hipStream_t stream)
{
  const float* images  = (const float*)d_in[0];
  const float* offset1 = (const float*)d_in[1];
  const float* w1  = (const float*)d_in[2];
  const float* g1  = (const float*)d_in[3];
  const float* b1  = (const float*)d_in[4];
  const float* w2  = (const float*)d_in[5];
  const float* g2  = (const float*)d_in[6];
  const float* b2  = (const float*)d_in[7];
  const float* w3a = (const float*)d_in[8];
  const float* w3b = (const float*)d_in[9];
  const float* w3c = (const float*)d_in[10];
  const float* w3d = (const float*)d_in[11];
  const float* g3a = (const float*)d_in[12];
  const float* b3a = (const float*)d_in[13];
  const float* g3b = (const float*)d_in[14];
  const float* b3b = (const float*)d_in[15];
  const float* g3c = (const float*)d_in[16];
  const float* b3c = (const float*)d_in[17];
  const float* g3d = (const float*)d_in[18];
  const float* b3d = (const float*)d_in[19];
  const float* w4  = (const float*)d_in[20];
  const float* b4  = (const float*)d_in[21];

  float* ws  = (float*)d_ws;
  float* out = (float*)d_out;

  float* statsY = ws + OFF_STATS_Y;
  float* statsX = ws + OFF_STATS_X2P;
  float* statsH = ws + OFF_STATS_H;
  float* pvol   = ws + OFF_PVOL;
  float* w1t    = ws + OFF_W1T;
  float* w2t    = ws + OFF_W2T;
  float* YH     = ws + OFF_YH;   // y, later H
  float* x2p    = ws + OFF_X2P;

  s0_setup<<<dim3(128), dim3(256), 0, stream>>>(images, offset1, w1, w2, w3a, w3b, w3c, w3d, w4, ws);
  s1_gather_gemm<<<dim3(128, 4), dim3(256), 0, stream>>>(pvol, ws + OFF_TPAR, w1t, YH, statsY);
  s2_bn_gemm<<<dim3(128, 4), dim3(256), 0, stream>>>(YH, statsY, g1, b1, w2t, x2p, statsX);
  s3_x2_ha<<<dim3(128, 2), dim3(256), 0, stream>>>(x2p, statsX, g2, b2, ws + OFF_W3AT, YH, statsH);
  s_dense<160><<<dim3(128, 2), dim3(256), 0, stream>>>(YH, statsH, g3a, b3a, ws + OFF_W3BT, YH, statsH, 160);
  s_dense<192><<<dim3(128, 2), dim3(256), 0, stream>>>(YH, statsH, g3b, b3b, ws + OFF_W3CT, YH, statsH, 192);
  s_dense<224><<<dim3(128, 2), dim3(256), 0, stream>>>(YH, statsH, g3c, b3c, ws + OFF_W3DT, YH, statsH, 224);
  s7_final<<<dim3(128), dim3(256), 0, stream>>>(YH, statsH, g3d, b3d, ws + OFF_W4T, b4, out);
}